// Round 1
// baseline (144.801 us; speedup 1.0000x reference)
//
#include <hip/hip_runtime.h>
#include <hip/hip_bf16.h>
#include <math.h>

#define DFEAT 128
#define KNBR  16
#define NPB   64   // nodes per block

typedef __attribute__((ext_vector_type(8))) short short8;
typedef __attribute__((ext_vector_type(4))) float f32x4;

__device__ __forceinline__ unsigned short f2bf(float x) {
    union { float f; unsigned u; } v; v.f = x;
    unsigned r = v.u + 0x7FFFu + ((v.u >> 16) & 1u);   // round-nearest-even
    return (unsigned short)(r >> 16);
}

// Build Wcat[j][0..255] = [w_self[j,:], w_nei[j,:]] in bf16 (row-major, K=256)
__global__ void prep_wcat_kernel(const float* __restrict__ wself,
                                 const float* __restrict__ wnei,
                                 unsigned short* __restrict__ wcat) {
    int t = blockIdx.x * 256 + threadIdx.x;
    if (t >= DFEAT * 256) return;
    int j = t >> 8;
    int d = t & 255;
    float v = (d < DFEAT) ? wself[j * DFEAT + d] : wnei[j * DFEAT + (d - DFEAT)];
    wcat[t] = f2bf(v);
}

__global__ __launch_bounds__(256)
void sage_fused_kernel(const float* __restrict__ h,
                       const int* __restrict__ nbr32,
                       const float* __restrict__ nbrw,
                       const unsigned short* __restrict__ wcat,
                       const float* __restrict__ gamma,
                       const float* __restrict__ beta,
                       float* __restrict__ out,
                       int N) {
    // x tile: 64 nodes x 256 k, bf16, XOR-swizzled on 16B chunks (c ^= row&7)
    __shared__ __align__(16) unsigned short xlds[NPB][256];   // 32 KB
    __shared__ __align__(16) float lsum[4][NPB];               // per-wave partial sums
    __shared__ __align__(16) float lsq[4][NPB];

    const int tid = threadIdx.x;
    const int nb  = blockIdx.x * NPB;

    // int64-vs-int32 index dtype detection (indices < 2^17, so int64 => all odd words 0)
    const bool idx64 = ((nbr32[1] | nbr32[3] | nbr32[5] | nbr32[7] |
                         nbr32[9] | nbr32[11] | nbr32[13] | nbr32[15]) == 0);

    // ---------------- Phase 1: gather + stage ----------------
    {
        const int q = tid & 31;   // lane in 32-group: owns dims [q*4, q*4+4)
        const int g = tid >> 5;   // group 0..7: owns nodes g*8..g*8+7
        for (int r = 0; r < 8; ++r) {
            const int i = g * 8 + r;
            int n = nb + i; if (n >= N) n = N - 1;
            const float4* hrow = (const float4*)(h + (long)n * DFEAT);
            float4 hv = hrow[q];

            f32x4 acc = {0.f, 0.f, 0.f, 0.f};
            #pragma unroll
            for (int k = 0; k < KNBR; ++k) {
                const int e = n * KNBR + k;
                float w = nbrw[e];
                int ei = idx64 ? (2 * e) : e;
                int idx = nbr32[ei];
                const float4* nrow = (const float4*)(h + (long)idx * DFEAT);
                float4 nv = nrow[q];
                acc[0] += w * nv.x; acc[1] += w * nv.y;
                acc[2] += w * nv.z; acc[3] += w * nv.w;
            }
            {   // h -> k = q*4
                int k = q * 4;
                int c = (k >> 3) ^ (i & 7);
                ushort4 b; b.x = f2bf(hv.x); b.y = f2bf(hv.y); b.z = f2bf(hv.z); b.w = f2bf(hv.w);
                *(ushort4*)&xlds[i][c * 8 + (k & 7)] = b;
            }
            {   // agg -> k = 128 + q*4
                int k = 128 + q * 4;
                int c = (k >> 3) ^ (i & 7);
                ushort4 b; b.x = f2bf(acc[0]); b.y = f2bf(acc[1]); b.z = f2bf(acc[2]); b.w = f2bf(acc[3]);
                *(ushort4*)&xlds[i][c * 8 + (k & 7)] = b;
            }
        }
    }
    __syncthreads();

    // ---------------- Phase 2: MFMA GEMM (64 nodes x 128 j, K=256) ----------------
    const int l   = tid & 63;
    const int wv  = tid >> 6;     // wave 0..3 owns j in [wv*32, wv*32+32)
    const int col = l & 15;
    const int kg  = l >> 4;       // 0..3

    f32x4 acc2[4][2];
    #pragma unroll
    for (int s = 0; s < 4; ++s)
        #pragma unroll
        for (int t = 0; t < 2; ++t)
            acc2[s][t] = (f32x4){0.f, 0.f, 0.f, 0.f};

    const unsigned short* wbase0 = wcat + (wv * 32 + col) * 256 + kg * 8;
    const unsigned short* wbase1 = wbase0 + 16 * 256;

    #pragma unroll
    for (int kk = 0; kk < 8; ++kk) {
        short8 b0 = *(const short8*)(wbase0 + kk * 32);   // B[k][col] = Wcat[j][k]
        short8 b1 = *(const short8*)(wbase1 + kk * 32);
        #pragma unroll
        for (int s = 0; s < 4; ++s) {
            const int row = s * 16 + col;                  // A row = node in tile
            const int c = (kk * 4 + kg) ^ (row & 7);       // swizzled 16B chunk
            short8 a = *(const short8*)&xlds[row][c * 8];
            acc2[s][0] = __builtin_amdgcn_mfma_f32_16x16x32_bf16(a, b0, acc2[s][0], 0, 0, 0);
            acc2[s][1] = __builtin_amdgcn_mfma_f32_16x16x32_bf16(a, b1, acc2[s][1], 0, 0, 0);
        }
    }

    // ---------------- Phase 3: GELU (exact erf) ----------------
    float y[4][2][4];
    #pragma unroll
    for (int s = 0; s < 4; ++s)
        #pragma unroll
        for (int t = 0; t < 2; ++t)
            #pragma unroll
            for (int r = 0; r < 4; ++r) {
                float x = acc2[s][t][r];
                y[s][t][r] = 0.5f * x * (1.0f + erff(x * 0.70710678118654752f));
            }

    // ---------------- Phase 4: LN stats (cross-lane then cross-wave) ----------------
    // D layout: row = kg*4 + r (node), col = l&15 (j)
    #pragma unroll
    for (int s = 0; s < 4; ++s) {
        f32x4 sm, sq;
        #pragma unroll
        for (int r = 0; r < 4; ++r) {
            float a0 = y[s][0][r], a1 = y[s][1][r];
            sm[r] = a0 + a1;
            sq[r] = a0 * a0 + a1 * a1;
        }
        #pragma unroll
        for (int m = 1; m < 16; m <<= 1) {
            #pragma unroll
            for (int r = 0; r < 4; ++r) {
                sm[r] += __shfl_xor(sm[r], m, 64);
                sq[r] += __shfl_xor(sq[r], m, 64);
            }
        }
        if (col == 0) {
            *(f32x4*)&lsum[wv][s * 16 + kg * 4] = sm;
            *(f32x4*)&lsq [wv][s * 16 + kg * 4] = sq;
        }
    }
    __syncthreads();

    // ---------------- Phase 5: LN apply + store ----------------
    const float g0  = gamma[wv * 32 + col];
    const float g1  = gamma[wv * 32 + 16 + col];
    const float be0 = beta [wv * 32 + col];
    const float be1 = beta [wv * 32 + 16 + col];

    #pragma unroll
    for (int s = 0; s < 4; ++s) {
        f32x4 sm = {0.f,0.f,0.f,0.f}, sq = {0.f,0.f,0.f,0.f};
        #pragma unroll
        for (int u = 0; u < 4; ++u) {
            f32x4 a = *(const f32x4*)&lsum[u][s * 16 + kg * 4];
            f32x4 b = *(const f32x4*)&lsq [u][s * 16 + kg * 4];
            sm += a; sq += b;
        }
        #pragma unroll
        for (int r = 0; r < 4; ++r) {
            const int i = s * 16 + kg * 4 + r;
            const int n = nb + i;
            if (n < N) {
                float mean = sm[r] * (1.0f / 128.0f);
                float var  = sq[r] * (1.0f / 128.0f) - mean * mean;
                float rstd = rsqrtf(var + 1e-5f);
                long o = (long)n * DFEAT + wv * 32 + col;
                out[o]      = (y[s][0][r] - mean) * rstd * g0 + be0;
                out[o + 16] = (y[s][1][r] - mean) * rstd * g1 + be1;
            }
        }
    }
}

extern "C" void kernel_launch(void* const* d_in, const int* in_sizes, int n_in,
                              void* d_out, int out_size, void* d_ws, size_t ws_size,
                              hipStream_t stream) {
    const float* h     = (const float*)d_in[0];
    const int*   nbr   = (const int*)  d_in[1];
    const float* nbrw  = (const float*)d_in[2];
    const float* wself = (const float*)d_in[3];
    const float* wnei  = (const float*)d_in[4];
    const float* gamma = (const float*)d_in[5];
    const float* beta  = (const float*)d_in[6];
    const int N = in_sizes[0] / DFEAT;

    unsigned short* wcat = (unsigned short*)d_ws;   // 64 KB bf16 Wcat

    prep_wcat_kernel<<<(DFEAT * 256 + 255) / 256, 256, 0, stream>>>(wself, wnei, wcat);

    const int blocks = (N + NPB - 1) / NPB;
    sage_fused_kernel<<<blocks, 256, 0, stream>>>(h, nbr, nbrw, wcat, gamma, beta,
                                                  (float*)d_out, N);
}

// Round 2
// 115.378 us; speedup vs baseline: 1.2550x; 1.2550x over previous
//
#include <hip/hip_runtime.h>
#include <hip/hip_bf16.h>
#include <math.h>

#define DFEAT 128
#define KNBR  16
#define NPB   64   // nodes per block

typedef __attribute__((ext_vector_type(8))) short short8;
typedef __attribute__((ext_vector_type(4))) float f32x4;

__device__ __forceinline__ unsigned short f2bf(float x) {
    union { float f; unsigned u; } v; v.f = x;
    unsigned r = v.u + 0x7FFFu + ((v.u >> 16) & 1u);   // round-nearest-even
    return (unsigned short)(r >> 16);
}
__device__ __forceinline__ float bf2f(unsigned short u) {
    union { unsigned u; float f; } v; v.u = ((unsigned)u) << 16; return v.f;
}

// ---- prep: Wcat[j][0..255] = [w_self[j,:], w_nei[j,:]] in bf16 ----
__global__ void prep_wcat_kernel(const float* __restrict__ wself,
                                 const float* __restrict__ wnei,
                                 unsigned short* __restrict__ wcat) {
    int t = blockIdx.x * 256 + threadIdx.x;
    if (t >= DFEAT * 256) return;
    int j = t >> 8;
    int d = t & 255;
    float v = (d < DFEAT) ? wself[j * DFEAT + d] : wnei[j * DFEAT + (d - DFEAT)];
    wcat[t] = f2bf(v);
}

// ---- prep: h (f32) -> h16 (bf16), 8 elems/thread ----
__global__ void prep_h16_kernel(const float* __restrict__ h,
                                unsigned short* __restrict__ h16, int ntot) {
    int t = blockIdx.x * 256 + threadIdx.x;
    if (t >= ntot) return;
    const float4* src = (const float4*)(h + (long)t * 8);
    float4 a = src[0], b = src[1];
    short8 o;
    o[0] = f2bf(a.x); o[1] = f2bf(a.y); o[2] = f2bf(a.z); o[3] = f2bf(a.w);
    o[4] = f2bf(b.x); o[5] = f2bf(b.y); o[6] = f2bf(b.z); o[7] = f2bf(b.w);
    *(short8*)(h16 + (long)t * 8) = o;
}

template<int H16>
__global__ __launch_bounds__(256, 4)
void sage_fused_kernel(const float* __restrict__ h,
                       const unsigned short* __restrict__ h16,
                       const int* __restrict__ nbr32,
                       const float* __restrict__ nbrw,
                       const unsigned short* __restrict__ wcat,
                       const float* __restrict__ gamma,
                       const float* __restrict__ beta,
                       float* __restrict__ out,
                       int N) {
    // x tile: 64 nodes x 256 k, bf16, XOR-swizzled on 16B chunks (c ^= row&7)
    __shared__ __align__(16) unsigned short xlds[NPB][256];   // 32 KB
    __shared__ __align__(16) float lsum[4][NPB];
    __shared__ __align__(16) float lsq[4][NPB];

    const int tid = threadIdx.x;
    const int nb  = blockIdx.x * NPB;

    // int64-vs-int32 index dtype detection (idx < 2^17 => int64 odd words all 0)
    const bool idx64 = ((nbr32[1] | nbr32[3] | nbr32[5] | nbr32[7] |
                         nbr32[9] | nbr32[11] | nbr32[13] | nbr32[15]) == 0);

    // ---------------- Phase 1: gather + stage ----------------
    {
        const int q = tid & 15;   // lane in 16-group: owns dims [q*8, q*8+8)
        const int g = tid >> 4;   // group 0..15: owns nodes g*4..g*4+3
        for (int r = 0; r < 4; ++r) {
            const int i = g * 4 + r;
            int n = nb + i; if (n >= N) n = N - 1;

            short8 hv;                    // self row, bf16
            float acc[8] = {0.f,0.f,0.f,0.f,0.f,0.f,0.f,0.f};

            if constexpr (H16) {
                hv = *(const short8*)(h16 + (long)n * DFEAT + q * 8);
                #pragma unroll
                for (int k = 0; k < KNBR; ++k) {
                    const int e = n * KNBR + k;
                    float w = nbrw[e];
                    int idx = nbr32[idx64 ? 2 * e : e];
                    short8 nv = *(const short8*)(h16 + (long)idx * DFEAT + q * 8);
                    #pragma unroll
                    for (int d = 0; d < 8; ++d)
                        acc[d] += w * bf2f((unsigned short)nv[d]);
                }
            } else {
                const float4* hrow = (const float4*)(h + (long)n * DFEAT + q * 8);
                float4 h0 = hrow[0], h1 = hrow[1];
                hv[0] = f2bf(h0.x); hv[1] = f2bf(h0.y); hv[2] = f2bf(h0.z); hv[3] = f2bf(h0.w);
                hv[4] = f2bf(h1.x); hv[5] = f2bf(h1.y); hv[6] = f2bf(h1.z); hv[7] = f2bf(h1.w);
                #pragma unroll
                for (int k = 0; k < KNBR; ++k) {
                    const int e = n * KNBR + k;
                    float w = nbrw[e];
                    int idx = nbr32[idx64 ? 2 * e : e];
                    const float4* nrow = (const float4*)(h + (long)idx * DFEAT + q * 8);
                    float4 n0 = nrow[0], n1 = nrow[1];
                    acc[0] += w * n0.x; acc[1] += w * n0.y;
                    acc[2] += w * n0.z; acc[3] += w * n0.w;
                    acc[4] += w * n1.x; acc[5] += w * n1.y;
                    acc[6] += w * n1.z; acc[7] += w * n1.w;
                }
            }

            // stage self row: chunk = q, swizzled
            *(short8*)&xlds[i][(q ^ (i & 7)) * 8] = hv;
            // stage agg: chunk = 16 + q, swizzled (XOR touches bits 0-2 only)
            short8 ab;
            #pragma unroll
            for (int d = 0; d < 8; ++d) ab[d] = f2bf(acc[d]);
            *(short8*)&xlds[i][((16 + q) ^ (i & 7)) * 8] = ab;
        }
    }
    __syncthreads();

    // ---------------- Phase 2: MFMA GEMM (64 nodes x 128 j, K=256) ----------------
    const int l   = tid & 63;
    const int wv  = tid >> 6;     // wave 0..3 owns j in [wv*32, wv*32+32)
    const int col = l & 15;
    const int kg  = l >> 4;       // 0..3

    f32x4 acc2[4][2];
    #pragma unroll
    for (int s = 0; s < 4; ++s)
        #pragma unroll
        for (int t = 0; t < 2; ++t)
            acc2[s][t] = (f32x4){0.f, 0.f, 0.f, 0.f};

    const unsigned short* wbase0 = wcat + (wv * 32 + col) * 256 + kg * 8;
    const unsigned short* wbase1 = wbase0 + 16 * 256;

    #pragma unroll
    for (int kk = 0; kk < 8; ++kk) {
        short8 b0 = *(const short8*)(wbase0 + kk * 32);   // B[k][col] = Wcat[j][k]
        short8 b1 = *(const short8*)(wbase1 + kk * 32);
        #pragma unroll
        for (int s = 0; s < 4; ++s) {
            const int row = s * 16 + col;                  // A row = node in tile
            const int c = (kk * 4 + kg) ^ (row & 7);       // swizzled 16B chunk
            short8 a = *(const short8*)&xlds[row][c * 8];
            acc2[s][0] = __builtin_amdgcn_mfma_f32_16x16x32_bf16(a, b0, acc2[s][0], 0, 0, 0);
            acc2[s][1] = __builtin_amdgcn_mfma_f32_16x16x32_bf16(a, b1, acc2[s][1], 0, 0, 0);
        }
    }

    // ---------------- Phase 3: GELU (exact erf) ----------------
    float y[4][2][4];
    #pragma unroll
    for (int s = 0; s < 4; ++s)
        #pragma unroll
        for (int t = 0; t < 2; ++t)
            #pragma unroll
            for (int r = 0; r < 4; ++r) {
                float x = acc2[s][t][r];
                y[s][t][r] = 0.5f * x * (1.0f + erff(x * 0.70710678118654752f));
            }

    // ---------------- Phase 4: LN stats ----------------
    #pragma unroll
    for (int s = 0; s < 4; ++s) {
        f32x4 sm, sq;
        #pragma unroll
        for (int r = 0; r < 4; ++r) {
            float a0 = y[s][0][r], a1 = y[s][1][r];
            sm[r] = a0 + a1;
            sq[r] = a0 * a0 + a1 * a1;
        }
        #pragma unroll
        for (int m = 1; m < 16; m <<= 1) {
            #pragma unroll
            for (int r = 0; r < 4; ++r) {
                sm[r] += __shfl_xor(sm[r], m, 64);
                sq[r] += __shfl_xor(sq[r], m, 64);
            }
        }
        if (col == 0) {
            *(f32x4*)&lsum[wv][s * 16 + kg * 4] = sm;
            *(f32x4*)&lsq [wv][s * 16 + kg * 4] = sq;
        }
    }
    __syncthreads();

    // ---------------- Phase 5: LN apply + store ----------------
    const float g0  = gamma[wv * 32 + col];
    const float g1  = gamma[wv * 32 + 16 + col];
    const float be0 = beta [wv * 32 + col];
    const float be1 = beta [wv * 32 + 16 + col];

    #pragma unroll
    for (int s = 0; s < 4; ++s) {
        f32x4 sm = {0.f,0.f,0.f,0.f}, sq = {0.f,0.f,0.f,0.f};
        #pragma unroll
        for (int u = 0; u < 4; ++u) {
            f32x4 a = *(const f32x4*)&lsum[u][s * 16 + kg * 4];
            f32x4 b = *(const f32x4*)&lsq [u][s * 16 + kg * 4];
            sm += a; sq += b;
        }
        #pragma unroll
        for (int r = 0; r < 4; ++r) {
            const int i = s * 16 + kg * 4 + r;
            const int n = nb + i;
            if (n < N) {
                float mean = sm[r] * (1.0f / 128.0f);
                float var  = sq[r] * (1.0f / 128.0f) - mean * mean;
                float rstd = rsqrtf(var + 1e-5f);
                long o = (long)n * DFEAT + wv * 32 + col;
                out[o]      = (y[s][0][r] - mean) * rstd * g0 + be0;
                out[o + 16] = (y[s][1][r] - mean) * rstd * g1 + be1;
            }
        }
    }
}

extern "C" void kernel_launch(void* const* d_in, const int* in_sizes, int n_in,
                              void* d_out, int out_size, void* d_ws, size_t ws_size,
                              hipStream_t stream) {
    const float* h     = (const float*)d_in[0];
    const int*   nbr   = (const int*)  d_in[1];
    const float* nbrw  = (const float*)d_in[2];
    const float* wself = (const float*)d_in[3];
    const float* wnei  = (const float*)d_in[4];
    const float* gamma = (const float*)d_in[5];
    const float* beta  = (const float*)d_in[6];
    const int N = in_sizes[0] / DFEAT;

    unsigned short* wcat = (unsigned short*)d_ws;               // 64 KB
    unsigned short* h16  = (unsigned short*)((char*)d_ws + 65536);
    const size_t need = 65536 + (size_t)N * DFEAT * sizeof(unsigned short);

    prep_wcat_kernel<<<(DFEAT * 256 + 255) / 256, 256, 0, stream>>>(wself, wnei, wcat);

    const int blocks = (N + NPB - 1) / NPB;
    if (ws_size >= need) {
        const int ntot = N * DFEAT / 8;
        prep_h16_kernel<<<(ntot + 255) / 256, 256, 0, stream>>>(h, h16, ntot);
        sage_fused_kernel<1><<<blocks, 256, 0, stream>>>(h, h16, nbr, nbrw, wcat,
                                                         gamma, beta, (float*)d_out, N);
    } else {
        sage_fused_kernel<0><<<blocks, 256, 0, stream>>>(h, (const unsigned short*)nullptr,
                                                         nbr, nbrw, wcat,
                                                         gamma, beta, (float*)d_out, N);
    }
}

// Round 3
// 95.787 us; speedup vs baseline: 1.5117x; 1.2045x over previous
//
#include <hip/hip_runtime.h>
#include <hip/hip_bf16.h>
#include <math.h>

#define DFEAT 128
#define KNBR  16
#define NPB   64   // nodes per block

typedef __attribute__((ext_vector_type(8))) short short8;
typedef __attribute__((ext_vector_type(4))) float f32x4;

__device__ __forceinline__ unsigned short f2bf(float x) {
    union { float f; unsigned u; } v; v.f = x;
    unsigned r = v.u + 0x7FFFu + ((v.u >> 16) & 1u);   // round-nearest-even
    return (unsigned short)(r >> 16);
}
__device__ __forceinline__ float bf2f(unsigned short u) {
    union { unsigned u; float f; } v; v.u = ((unsigned)u) << 16; return v.f;
}

// ---- fused prep: wcat (first 4096 threads) + h16 (rest), 8 elems/thread ----
__global__ __launch_bounds__(256)
void prep_kernel(const float* __restrict__ h,
                 const float* __restrict__ wself,
                 const float* __restrict__ wnei,
                 unsigned short* __restrict__ h16,
                 unsigned short* __restrict__ wcat,
                 int ntot8) {
    const int t = blockIdx.x * 256 + threadIdx.x;
    if (t < 4096) {
        // Wcat[j][0..255] = [w_self[j,:], w_nei[j,:]] bf16
        const int base = t * 8;
        const int j = base >> 8;
        const int d0 = base & 255;
        const float* src = (d0 < DFEAT) ? (wself + j * DFEAT + d0)
                                        : (wnei  + j * DFEAT + (d0 - DFEAT));
        float4 a = ((const float4*)src)[0], b = ((const float4*)src)[1];
        short8 o;
        o[0] = f2bf(a.x); o[1] = f2bf(a.y); o[2] = f2bf(a.z); o[3] = f2bf(a.w);
        o[4] = f2bf(b.x); o[5] = f2bf(b.y); o[6] = f2bf(b.z); o[7] = f2bf(b.w);
        *(short8*)(wcat + base) = o;
        return;
    }
    const long u = (long)t - 4096;
    if (u >= ntot8) return;
    const float4* src = (const float4*)(h + u * 8);
    float4 a = src[0], b = src[1];
    short8 o;
    o[0] = f2bf(a.x); o[1] = f2bf(a.y); o[2] = f2bf(a.z); o[3] = f2bf(a.w);
    o[4] = f2bf(b.x); o[5] = f2bf(b.y); o[6] = f2bf(b.z); o[7] = f2bf(b.w);
    *(short8*)(h16 + u * 8) = o;
}

template<int H16>
__global__ __launch_bounds__(256, 4)
void sage_fused_kernel(const float* __restrict__ h,
                       const unsigned short* __restrict__ h16,
                       const int* __restrict__ nbr32,
                       const float* __restrict__ nbrw,
                       const unsigned short* __restrict__ wcat,
                       const float* __restrict__ gamma,
                       const float* __restrict__ beta,
                       float* __restrict__ out,
                       int N) {
    // x tile: 64 nodes x 256 k, bf16, XOR-swizzled on 16B chunks (c ^= row&7)
    // LN scratch is OVERLAID on xlds (dead after the MFMA loop) -> 32 KB total
    __shared__ __align__(16) unsigned short xlds[NPB][256];   // 32 KB exactly

    const int tid = threadIdx.x;
    const int nb  = blockIdx.x * NPB;

    // int64-vs-int32 index dtype detection (idx < 2^17 => int64 odd words all 0)
    const bool idx64 = ((nbr32[1] | nbr32[3] | nbr32[5] | nbr32[7] |
                         nbr32[9] | nbr32[11] | nbr32[13] | nbr32[15]) == 0);

    const int l   = tid & 63;
    const int wvi = tid >> 6;     // wave 0..3
    const int q   = l & 15;       // lane-in-group: dims [q*8, q*8+8)
    const int gb  = l & 48;       // group base lane within wave

    // ---------------- Phase 1: gather + stage ----------------
    #pragma unroll 1
    for (int r = 0; r < 4; ++r) {
        const int i = wvi * 16 + (l >> 4) * 4 + r;   // node-in-tile
        int n = nb + i; if (n >= N) n = N - 1;

        short8 hv;
        float acc[8] = {0.f,0.f,0.f,0.f,0.f,0.f,0.f,0.f};

        if constexpr (H16) {
            // each lane owns ONE edge of its group's node; share via shfl
            const int e = n * KNBR + q;
            const int   myidx = __builtin_nontemporal_load(&nbr32[idx64 ? 2 * e : e]);
            const float myw   = __builtin_nontemporal_load(&nbrw[e]);

            hv = *(const short8*)(h16 + (long)n * DFEAT + q * 8);

            short8 nv[16];   // all 16 rows in flight
            #pragma unroll
            for (int k = 0; k < 16; ++k) {
                int ik = __shfl(myidx, gb + k, 64);
                nv[k] = *(const short8*)(h16 + (long)ik * DFEAT + q * 8);
            }
            #pragma unroll
            for (int k = 0; k < 16; ++k) {
                float wk = __shfl(myw, gb + k, 64);
                #pragma unroll
                for (int d = 0; d < 8; ++d)
                    acc[d] += wk * bf2f((unsigned short)nv[k][d]);
            }
        } else {
            const float4* hrow = (const float4*)(h + (long)n * DFEAT + q * 8);
            float4 h0 = hrow[0], h1 = hrow[1];
            hv[0] = f2bf(h0.x); hv[1] = f2bf(h0.y); hv[2] = f2bf(h0.z); hv[3] = f2bf(h0.w);
            hv[4] = f2bf(h1.x); hv[5] = f2bf(h1.y); hv[6] = f2bf(h1.z); hv[7] = f2bf(h1.w);
            const int e0 = n * KNBR;
            #pragma unroll 4
            for (int k = 0; k < KNBR; ++k) {
                float w = nbrw[e0 + k];
                int idx = nbr32[idx64 ? 2 * (e0 + k) : (e0 + k)];
                const float4* nrow = (const float4*)(h + (long)idx * DFEAT + q * 8);
                float4 n0 = nrow[0], n1 = nrow[1];
                acc[0] += w * n0.x; acc[1] += w * n0.y;
                acc[2] += w * n0.z; acc[3] += w * n0.w;
                acc[4] += w * n1.x; acc[5] += w * n1.y;
                acc[6] += w * n1.z; acc[7] += w * n1.w;
            }
        }

        // stage self row: chunk = q, swizzled
        *(short8*)&xlds[i][(q ^ (i & 7)) * 8] = hv;
        // stage agg: chunk = 16 + q, swizzled (XOR touches bits 0-2 only)
        short8 ab;
        #pragma unroll
        for (int d = 0; d < 8; ++d) ab[d] = f2bf(acc[d]);
        *(short8*)&xlds[i][((16 + q) ^ (i & 7)) * 8] = ab;
    }
    __syncthreads();

    // ---------------- Phase 2: MFMA GEMM (64 nodes x 128 j, K=256) ----------------
    const int wv  = wvi;          // wave owns j in [wv*32, wv*32+32)
    const int col = l & 15;
    const int kg  = l >> 4;       // 0..3

    f32x4 acc2[4][2];
    #pragma unroll
    for (int s = 0; s < 4; ++s)
        #pragma unroll
        for (int t = 0; t < 2; ++t)
            acc2[s][t] = (f32x4){0.f, 0.f, 0.f, 0.f};

    const unsigned short* wbase0 = wcat + (wv * 32 + col) * 256 + kg * 8;
    const unsigned short* wbase1 = wbase0 + 16 * 256;

    #pragma unroll
    for (int kk = 0; kk < 8; ++kk) {
        short8 b0 = *(const short8*)(wbase0 + kk * 32);   // B[k][col] = Wcat[j][k]
        short8 b1 = *(const short8*)(wbase1 + kk * 32);
        #pragma unroll
        for (int s = 0; s < 4; ++s) {
            const int row = s * 16 + col;                  // A row = node in tile
            const int c = (kk * 4 + kg) ^ (row & 7);       // swizzled 16B chunk
            short8 a = *(const short8*)&xlds[row][c * 8];
            acc2[s][0] = __builtin_amdgcn_mfma_f32_16x16x32_bf16(a, b0, acc2[s][0], 0, 0, 0);
            acc2[s][1] = __builtin_amdgcn_mfma_f32_16x16x32_bf16(a, b1, acc2[s][1], 0, 0, 0);
        }
    }

    // ---------------- Phase 3: GELU (exact erf) ----------------
    float y[4][2][4];
    #pragma unroll
    for (int s = 0; s < 4; ++s)
        #pragma unroll
        for (int t = 0; t < 2; ++t)
            #pragma unroll
            for (int r = 0; r < 4; ++r) {
                float x = acc2[s][t][r];
                y[s][t][r] = 0.5f * x * (1.0f + erff(x * 0.70710678118654752f));
            }

    __syncthreads();   // all xlds reads done before LN-scratch overlay writes

    // overlay LN scratch on the dead x tile
    float* lsum = (float*)&xlds[0][0];        // [4][64]
    float* lsq  = lsum + 4 * NPB;             // [4][64]

    // ---------------- Phase 4: LN stats ----------------
    #pragma unroll
    for (int s = 0; s < 4; ++s) {
        f32x4 sm, sq;
        #pragma unroll
        for (int r = 0; r < 4; ++r) {
            float a0 = y[s][0][r], a1 = y[s][1][r];
            sm[r] = a0 + a1;
            sq[r] = a0 * a0 + a1 * a1;
        }
        #pragma unroll
        for (int m = 1; m < 16; m <<= 1) {
            #pragma unroll
            for (int r = 0; r < 4; ++r) {
                sm[r] += __shfl_xor(sm[r], m, 64);
                sq[r] += __shfl_xor(sq[r], m, 64);
            }
        }
        if (col == 0) {
            *(f32x4*)&lsum[wv * NPB + s * 16 + kg * 4] = sm;
            *(f32x4*)&lsq [wv * NPB + s * 16 + kg * 4] = sq;
        }
    }
    __syncthreads();

    // ---------------- Phase 5: LN apply + store (non-temporal) ----------------
    const float g0  = gamma[wv * 32 + col];
    const float g1  = gamma[wv * 32 + 16 + col];
    const float be0 = beta [wv * 32 + col];
    const float be1 = beta [wv * 32 + 16 + col];

    #pragma unroll
    for (int s = 0; s < 4; ++s) {
        f32x4 sm = {0.f,0.f,0.f,0.f}, sq = {0.f,0.f,0.f,0.f};
        #pragma unroll
        for (int u = 0; u < 4; ++u) {
            f32x4 a = *(const f32x4*)&lsum[u * NPB + s * 16 + kg * 4];
            f32x4 b = *(const f32x4*)&lsq [u * NPB + s * 16 + kg * 4];
            sm += a; sq += b;
        }
        #pragma unroll
        for (int r = 0; r < 4; ++r) {
            const int i = s * 16 + kg * 4 + r;
            const int n = nb + i;
            if (n < N) {
                float mean = sm[r] * (1.0f / 128.0f);
                float var  = sq[r] * (1.0f / 128.0f) - mean * mean;
                float rstd = rsqrtf(var + 1e-5f);
                long o = (long)n * DFEAT + wv * 32 + col;
                __builtin_nontemporal_store((y[s][0][r] - mean) * rstd * g0 + be0, &out[o]);
                __builtin_nontemporal_store((y[s][1][r] - mean) * rstd * g1 + be1, &out[o + 16]);
            }
        }
    }
}

extern "C" void kernel_launch(void* const* d_in, const int* in_sizes, int n_in,
                              void* d_out, int out_size, void* d_ws, size_t ws_size,
                              hipStream_t stream) {
    const float* h     = (const float*)d_in[0];
    const int*   nbr   = (const int*)  d_in[1];
    const float* nbrw  = (const float*)d_in[2];
    const float* wself = (const float*)d_in[3];
    const float* wnei  = (const float*)d_in[4];
    const float* gamma = (const float*)d_in[5];
    const float* beta  = (const float*)d_in[6];
    const int N = in_sizes[0] / DFEAT;

    unsigned short* wcat = (unsigned short*)d_ws;               // 64 KB
    unsigned short* h16  = (unsigned short*)((char*)d_ws + 65536);
    const size_t need = 65536 + (size_t)N * DFEAT * sizeof(unsigned short);

    const int blocks = (N + NPB - 1) / NPB;
    if (ws_size >= need) {
        const int ntot8 = N * DFEAT / 8;
        const int pthreads = 4096 + ntot8;
        prep_kernel<<<(pthreads + 255) / 256, 256, 0, stream>>>(h, wself, wnei, h16, wcat, ntot8);
        sage_fused_kernel<1><<<blocks, 256, 0, stream>>>(h, h16, nbr, nbrw, wcat,
                                                         gamma, beta, (float*)d_out, N);
    } else {
        // fallback: no room for h16 table — gather f32 directly; still need wcat
        prep_kernel<<<(4096 + 255) / 256, 256, 0, stream>>>(h, wself, wnei, h16, wcat, 0);
        sage_fused_kernel<0><<<blocks, 256, 0, stream>>>(h, (const unsigned short*)nullptr,
                                                         nbr, nbrw, wcat,
                                                         gamma, beta, (float*)d_out, N);
    }
}

// Round 5
// 94.525 us; speedup vs baseline: 1.5319x; 1.0134x over previous
//
#include <hip/hip_runtime.h>
#include <hip/hip_bf16.h>
#include <math.h>

#define DFEAT 128
#define KNBR  16
#define NPB   64   // nodes per block

typedef __attribute__((ext_vector_type(8))) short short8;
typedef __attribute__((ext_vector_type(4))) float f32x4;

__device__ __forceinline__ unsigned short f2bf(float x) {
    union { float f; unsigned u; } v; v.f = x;
    unsigned r = v.u + 0x7FFFu + ((v.u >> 16) & 1u);   // round-nearest-even
    return (unsigned short)(r >> 16);
}
__device__ __forceinline__ float bf2f(unsigned short u) {
    union { unsigned u; float f; } v; v.u = ((unsigned)u) << 16; return v.f;
}

// ---- fused prep: wcat (first 4096 threads) + h16 (rest), 8 elems/thread ----
__global__ __launch_bounds__(256)
void prep_kernel(const float* __restrict__ h,
                 const float* __restrict__ wself,
                 const float* __restrict__ wnei,
                 unsigned short* __restrict__ h16,
                 unsigned short* __restrict__ wcat,
                 int ntot8) {
    const int t = blockIdx.x * 256 + threadIdx.x;
    if (t < 4096) {
        const int base = t * 8;
        const int j = base >> 8;
        const int d0 = base & 255;
        const float* src = (d0 < DFEAT) ? (wself + j * DFEAT + d0)
                                        : (wnei  + j * DFEAT + (d0 - DFEAT));
        f32x4 a = ((const f32x4*)src)[0], b = ((const f32x4*)src)[1];
        short8 o;
        o[0] = f2bf(a[0]); o[1] = f2bf(a[1]); o[2] = f2bf(a[2]); o[3] = f2bf(a[3]);
        o[4] = f2bf(b[0]); o[5] = f2bf(b[1]); o[6] = f2bf(b[2]); o[7] = f2bf(b[3]);
        *(short8*)(wcat + base) = o;
        return;
    }
    const long u = (long)t - 4096;
    if (u >= ntot8) return;
    f32x4 a = __builtin_nontemporal_load((const f32x4*)(h + u * 8));
    f32x4 b = __builtin_nontemporal_load((const f32x4*)(h + u * 8) + 1);
    short8 o;
    o[0] = f2bf(a[0]); o[1] = f2bf(a[1]); o[2] = f2bf(a[2]); o[3] = f2bf(a[3]);
    o[4] = f2bf(b[0]); o[5] = f2bf(b[1]); o[6] = f2bf(b[2]); o[7] = f2bf(b[3]);
    __builtin_nontemporal_store(o, (short8*)(h16 + u * 8));
}

template<int H16>
__global__ __launch_bounds__(256, 4)
void sage_fused_kernel(const float* __restrict__ h,
                       const unsigned short* __restrict__ h16,
                       const int* __restrict__ nbr32,
                       const float* __restrict__ nbrw,
                       const unsigned short* __restrict__ wcat,
                       const float* __restrict__ gamma,
                       const float* __restrict__ beta,
                       float* __restrict__ out,
                       int N) {
    // x tile: 64 nodes x 256 k, bf16, XOR-swizzled on 16B chunks (c ^= row&7)
    // LN scratch is OVERLAID on xlds (dead after the MFMA loop) -> 32 KB total
    __shared__ __align__(16) unsigned short xlds[NPB][256];   // 32 KB exactly

    const int tid = threadIdx.x;
    const int nb  = blockIdx.x * NPB;

    // int64-vs-int32 index dtype detection (idx < 2^17 => int64 odd words all 0)
    const bool idx64 = ((nbr32[1] | nbr32[3] | nbr32[5] | nbr32[7] |
                         nbr32[9] | nbr32[11] | nbr32[13] | nbr32[15]) == 0);

    const int l   = tid & 63;
    const int wvi = tid >> 6;     // wave 0..3
    const int q   = l & 15;       // lane-in-group: dims [q*8, q*8+8)
    const int gb  = l & 48;       // group base lane within wave
    const int i0  = wvi * 16 + (l >> 4) * 4;   // first node-in-tile of this group

    // ---------------- Phase 1: gather + stage (software-pipelined) ----------------
    if constexpr (H16) {
        // per-lane edge ownership: lane q owns edge q of each of its group's 4 nodes
        int   nn[4]; int myidx[4]; float myw[4]; short8 hv[4];
        #pragma unroll
        for (int r = 0; r < 4; ++r) {
            int n = nb + i0 + r; if (n >= N) n = N - 1;
            nn[r] = n;
            const int e = n * KNBR + q;
            myidx[r] = __builtin_nontemporal_load(&nbr32[idx64 ? 2 * e : e]);
            myw[r]   = __builtin_nontemporal_load(&nbrw[e]);
        }
        #pragma unroll
        for (int r = 0; r < 4; ++r)
            hv[r] = *(const short8*)(h16 + (long)nn[r] * DFEAT + q * 8);

        short8 bufA[8], bufB[8];   // two 8-row halves in flight
        float  acc[8];

        // ISSUE half hh (k = hh*8 .. hh*8+7) of node r into BUF
        #define ISSUE(BUF, r, hh)                                             \
            _Pragma("unroll")                                                 \
            for (int k8 = 0; k8 < 8; ++k8) {                                  \
                int ik = __shfl(myidx[r], gb + (hh) * 8 + k8, 64);            \
                BUF[k8] = *(const short8*)(h16 + (long)ik * DFEAT + q * 8);   \
            }
        // CONSUME half hh of node r from BUF into acc
        #define CONSUME(BUF, r, hh)                                           \
            _Pragma("unroll")                                                 \
            for (int k8 = 0; k8 < 8; ++k8) {                                  \
                float wk = __shfl(myw[r], gb + (hh) * 8 + k8, 64);            \
                _Pragma("unroll")                                             \
                for (int d = 0; d < 8; ++d)                                   \
                    acc[d] += wk * bf2f((unsigned short)BUF[k8][d]);          \
            }
        #define RESET() { _Pragma("unroll") for (int d = 0; d < 8; ++d) acc[d] = 0.f; }
        #define STORE(r) {                                                    \
            const int i = i0 + (r);                                           \
            *(short8*)&xlds[i][(q ^ (i & 7)) * 8] = hv[r];                    \
            short8 ab;                                                        \
            _Pragma("unroll") for (int d = 0; d < 8; ++d) ab[d] = f2bf(acc[d]); \
            *(short8*)&xlds[i][((16 + q) ^ (i & 7)) * 8] = ab; }

        ISSUE(bufA, 0, 0); ISSUE(bufB, 0, 1);
        RESET(); CONSUME(bufA, 0, 0); ISSUE(bufA, 1, 0);
                 CONSUME(bufB, 0, 1); ISSUE(bufB, 1, 1); STORE(0);
        RESET(); CONSUME(bufA, 1, 0); ISSUE(bufA, 2, 0);
                 CONSUME(bufB, 1, 1); ISSUE(bufB, 2, 1); STORE(1);
        RESET(); CONSUME(bufA, 2, 0); ISSUE(bufA, 3, 0);
                 CONSUME(bufB, 2, 1); ISSUE(bufB, 3, 1); STORE(2);
        RESET(); CONSUME(bufA, 3, 0);
                 CONSUME(bufB, 3, 1); STORE(3);
        #undef ISSUE
        #undef CONSUME
        #undef RESET
        #undef STORE
    } else {
        #pragma unroll 1
        for (int r = 0; r < 4; ++r) {
            const int i = i0 + r;
            int n = nb + i; if (n >= N) n = N - 1;
            short8 hv;
            float acc[8] = {0.f,0.f,0.f,0.f,0.f,0.f,0.f,0.f};
            const f32x4* hrow = (const f32x4*)(h + (long)n * DFEAT + q * 8);
            f32x4 h0 = hrow[0], h1 = hrow[1];
            hv[0] = f2bf(h0[0]); hv[1] = f2bf(h0[1]); hv[2] = f2bf(h0[2]); hv[3] = f2bf(h0[3]);
            hv[4] = f2bf(h1[0]); hv[5] = f2bf(h1[1]); hv[6] = f2bf(h1[2]); hv[7] = f2bf(h1[3]);
            const int e0 = n * KNBR;
            #pragma unroll 4
            for (int k = 0; k < KNBR; ++k) {
                float w = nbrw[e0 + k];
                int idx = nbr32[idx64 ? 2 * (e0 + k) : (e0 + k)];
                const f32x4* nrow = (const f32x4*)(h + (long)idx * DFEAT + q * 8);
                f32x4 n0 = nrow[0], n1 = nrow[1];
                acc[0] += w * n0[0]; acc[1] += w * n0[1];
                acc[2] += w * n0[2]; acc[3] += w * n0[3];
                acc[4] += w * n1[0]; acc[5] += w * n1[1];
                acc[6] += w * n1[2]; acc[7] += w * n1[3];
            }
            *(short8*)&xlds[i][(q ^ (i & 7)) * 8] = hv;
            short8 ab;
            #pragma unroll
            for (int d = 0; d < 8; ++d) ab[d] = f2bf(acc[d]);
            *(short8*)&xlds[i][((16 + q) ^ (i & 7)) * 8] = ab;
        }
    }
    __syncthreads();

    // ---------------- Phase 2: MFMA GEMM (64 nodes x 128 j, K=256) ----------------
    const int wv  = wvi;          // wave owns j in [wv*32, wv*32+32)
    const int col = l & 15;
    const int kg  = l >> 4;       // 0..3

    f32x4 acc2[4][2];
    #pragma unroll
    for (int s = 0; s < 4; ++s)
        #pragma unroll
        for (int t = 0; t < 2; ++t)
            acc2[s][t] = (f32x4){0.f, 0.f, 0.f, 0.f};

    const unsigned short* wbase0 = wcat + (wv * 32 + col) * 256 + kg * 8;
    const unsigned short* wbase1 = wbase0 + 16 * 256;

    #pragma unroll
    for (int kk = 0; kk < 8; ++kk) {
        short8 b0 = *(const short8*)(wbase0 + kk * 32);   // B[k][col] = Wcat[j][k]
        short8 b1 = *(const short8*)(wbase1 + kk * 32);
        #pragma unroll
        for (int s = 0; s < 4; ++s) {
            const int row = s * 16 + col;                  // A row = node in tile
            const int c = (kk * 4 + kg) ^ (row & 7);       // swizzled 16B chunk
            short8 a = *(const short8*)&xlds[row][c * 8];
            acc2[s][0] = __builtin_amdgcn_mfma_f32_16x16x32_bf16(a, b0, acc2[s][0], 0, 0, 0);
            acc2[s][1] = __builtin_amdgcn_mfma_f32_16x16x32_bf16(a, b1, acc2[s][1], 0, 0, 0);
        }
    }

    // ---------------- Phase 3: GELU (exact erf) ----------------
    float y[4][2][4];
    #pragma unroll
    for (int s = 0; s < 4; ++s)
        #pragma unroll
        for (int t = 0; t < 2; ++t)
            #pragma unroll
            for (int r = 0; r < 4; ++r) {
                float x = acc2[s][t][r];
                y[s][t][r] = 0.5f * x * (1.0f + erff(x * 0.70710678118654752f));
            }

    __syncthreads();   // all xlds reads done before LN-scratch overlay writes

    // overlay LN scratch on the dead x tile
    float* lsum = (float*)&xlds[0][0];        // [4][64]
    float* lsq  = lsum + 4 * NPB;             // [4][64]

    // ---------------- Phase 4: LN stats ----------------
    #pragma unroll
    for (int s = 0; s < 4; ++s) {
        f32x4 sm, sq;
        #pragma unroll
        for (int r = 0; r < 4; ++r) {
            float a0 = y[s][0][r], a1 = y[s][1][r];
            sm[r] = a0 + a1;
            sq[r] = a0 * a0 + a1 * a1;
        }
        #pragma unroll
        for (int m = 1; m < 16; m <<= 1) {
            #pragma unroll
            for (int r = 0; r < 4; ++r) {
                sm[r] += __shfl_xor(sm[r], m, 64);
                sq[r] += __shfl_xor(sq[r], m, 64);
            }
        }
        if (col == 0) {
            *(f32x4*)&lsum[wv * NPB + s * 16 + kg * 4] = sm;
            *(f32x4*)&lsq [wv * NPB + s * 16 + kg * 4] = sq;
        }
    }
    __syncthreads();

    // ---------------- Phase 5: LN apply + store (non-temporal) ----------------
    const float g0  = gamma[wv * 32 + col];
    const float g1  = gamma[wv * 32 + 16 + col];
    const float be0 = beta [wv * 32 + col];
    const float be1 = beta [wv * 32 + 16 + col];

    #pragma unroll
    for (int s = 0; s < 4; ++s) {
        f32x4 sm = {0.f,0.f,0.f,0.f}, sq = {0.f,0.f,0.f,0.f};
        #pragma unroll
        for (int u = 0; u < 4; ++u) {
            f32x4 a = *(const f32x4*)&lsum[u * NPB + s * 16 + kg * 4];
            f32x4 b = *(const f32x4*)&lsq [u * NPB + s * 16 + kg * 4];
            sm += a; sq += b;
        }
        #pragma unroll
        for (int r = 0; r < 4; ++r) {
            const int i = s * 16 + kg * 4 + r;
            const int n = nb + i;
            if (n < N) {
                float mean = sm[r] * (1.0f / 128.0f);
                float var  = sq[r] * (1.0f / 128.0f) - mean * mean;
                float rstd = rsqrtf(var + 1e-5f);
                long o = (long)n * DFEAT + wv * 32 + col;
                __builtin_nontemporal_store((y[s][0][r] - mean) * rstd * g0 + be0, &out[o]);
                __builtin_nontemporal_store((y[s][1][r] - mean) * rstd * g1 + be1, &out[o + 16]);
            }
        }
    }
}

extern "C" void kernel_launch(void* const* d_in, const int* in_sizes, int n_in,
                              void* d_out, int out_size, void* d_ws, size_t ws_size,
                              hipStream_t stream) {
    const float* h     = (const float*)d_in[0];
    const int*   nbr   = (const int*)  d_in[1];
    const float* nbrw  = (const float*)d_in[2];
    const float* wself = (const float*)d_in[3];
    const float* wnei  = (const float*)d_in[4];
    const float* gamma = (const float*)d_in[5];
    const float* beta  = (const float*)d_in[6];
    const int N = in_sizes[0] / DFEAT;

    unsigned short* wcat = (unsigned short*)d_ws;               // 64 KB
    unsigned short* h16  = (unsigned short*)((char*)d_ws + 65536);
    const size_t need = 65536 + (size_t)N * DFEAT * sizeof(unsigned short);

    const int blocks = (N + NPB - 1) / NPB;
    if (ws_size >= need) {
        const int ntot8 = N * DFEAT / 8;
        const int pthreads = 4096 + ntot8;
        prep_kernel<<<(pthreads + 255) / 256, 256, 0, stream>>>(h, wself, wnei, h16, wcat, ntot8);
        sage_fused_kernel<1><<<blocks, 256, 0, stream>>>(h, h16, nbr, nbrw, wcat,
                                                         gamma, beta, (float*)d_out, N);
    } else {
        prep_kernel<<<(4096 + 255) / 256, 256, 0, stream>>>(h, wself, wnei, h16, wcat, 0);
        sage_fused_kernel<0><<<blocks, 256, 0, stream>>>(h, (const unsigned short*)nullptr,
                                                         nbr, nbrw, wcat,
                                                         gamma, beta, (float*)d_out, N);
    }
}